// Round 6
// baseline (322.171 us; speedup 1.0000x reference)
//
#include <hip/hip_runtime.h>

#define TMAXV 100000
#define CHUNK 256
#define NCHUNK ((TMAXV + CHUNK - 1) / CHUNK)   // 391
#define WB 256                                  // bucket width in t
#define LOGWB 8
#define SB ((TMAXV + WB - 1) / WB)              // 391 buckets
#define TILE 4096
#define RPT 16                                  // records per thread (TILE/256)
#define KS 4                                    // slices per bucket in hist phase

// ---------------- block reduce helper (blockDim.x == 256) ----------------
__device__ __forceinline__ float block_reduce_sum(float v, float* sdata) {
    int lane = threadIdx.x & 63;
    int wid  = threadIdx.x >> 6;
    #pragma unroll
    for (int off = 32; off > 0; off >>= 1)
        v += __shfl_down(v, off, 64);
    if (lane == 0) sdata[wid] = v;
    __syncthreads();
    if (wid == 0) {
        v = (lane < 4) ? sdata[lane] : 0.0f;
        v += __shfl_down(v, 2, 64);
        v += __shfl_down(v, 1, 64);
    }
    return v;  // valid in thread 0
}

// ================= FAST PATH: atomic-free tiled counting sort =============

// ---- P1: per-tile bucket counts (LDS), no global atomics ----
__global__ void count_kernel(const int* __restrict__ tgt,
                             int* __restrict__ blkcnt, int n, int nt) {
    __shared__ int lc[SB];
    for (int i = threadIdx.x; i < SB; i += blockDim.x) lc[i] = 0;
    __syncthreads();
    int tile = blockIdx.x;
    int lo = tile * TILE;
    int hi = min(n, lo + TILE);
    for (int i = lo + threadIdx.x; i < hi; i += blockDim.x)
        atomicAdd(&lc[tgt[i] >> LOGWB], 1);
    __syncthreads();
    for (int s = threadIdx.x; s < SB; s += blockDim.x)
        blkcnt[s * nt + tile] = lc[s];
}

// ---- P2a: per-bucket exclusive scan over tiles ----
__global__ void tile_scan_kernel(const int* __restrict__ blkcnt,
                                 int* __restrict__ tilebase,
                                 int* __restrict__ totals, int nt) {
    __shared__ int ls[256];
    int s   = blockIdx.x;
    int tid = threadIdx.x;
    int run = 0;
    for (int t0 = 0; t0 < nt; t0 += 256) {
        int t = t0 + tid;
        int c = (t < nt) ? blkcnt[s * nt + t] : 0;
        ls[tid] = c;
        __syncthreads();
        for (int off = 1; off < 256; off <<= 1) {
            int a = (tid >= off) ? ls[tid - off] : 0;
            __syncthreads();
            ls[tid] += a;
            __syncthreads();
        }
        int incl = ls[tid];
        int tot  = ls[255];
        if (t < nt) tilebase[s * nt + t] = run + incl - c;
        run += tot;
        __syncthreads();
    }
    if (tid == 0) totals[s] = run;
}

// ---- P2b: exclusive scan of bucket totals -> base (512 threads) ----
__global__ void bucket_base_kernel(const int* __restrict__ totals,
                                   int* __restrict__ base, int n) {
    __shared__ int ls[512];
    int tid = threadIdx.x;
    int c = (tid < SB) ? totals[tid] : 0;
    ls[tid] = c;
    __syncthreads();
    for (int off = 1; off < 512; off <<= 1) {
        int a = (tid >= off) ? ls[tid - off] : 0;
        __syncthreads();
        ls[tid] += a;
        __syncthreads();
    }
    if (tid < SB) base[tid] = ls[tid] - c;
    if (tid == 0) base[SB] = n;
}

// ---- P3: LDS-staged scatter of 5-byte records (val + slot byte) ----------
// val sign bit = event flag; log_nom total reduced here into acc[2].
__global__ void scatter_kernel(const float* __restrict__ lh,
                               const int*   __restrict__ tgt,
                               const int*   __restrict__ ev,
                               const int*   __restrict__ tilebase,
                               const int*   __restrict__ base,
                               float* __restrict__ val,
                               unsigned char* __restrict__ slotArr,
                               double* __restrict__ acc, int n, int nt) {
    __shared__ float fv[TILE];              // 16 KB
    __shared__ unsigned char fs[TILE];      // 4 KB
    __shared__ int lcnt[SB];
    __shared__ int pfx[SB];
    __shared__ int lrank[SB];
    __shared__ int tb[SB];
    __shared__ int ls[512];
    __shared__ float sdata[4];
    int tid  = threadIdx.x;
    int tile = blockIdx.x;
    int lo   = tile * TILE;
    int cnt_here = min(TILE, n - lo);

    for (int s = tid; s < SB; s += 256) {
        lcnt[s]  = 0;
        lrank[s] = 0;
        tb[s]    = base[s] + tilebase[s * nt + tile];
    }
    __syncthreads();

    float    rv[RPT];
    unsigned rt[RPT];
    float xl = 0.f;
    #pragma unroll
    for (int k = 0; k < RPT; ++k) {
        int i = lo + k * 256 + tid;
        if (i < n) {
            int t = tgt[i];
            int e = ev[i] & 1;
            float x = lh[i];
            float h = __expf(x);
            rv[k] = e ? -h : h;
            rt[k] = (unsigned)t;
            if (e) xl += x;
            atomicAdd(&lcnt[t >> LOGWB], 1);
        } else {
            rt[k] = 0xFFFFFFFFu;
        }
    }
    __syncthreads();

    // exclusive scan of lcnt[0..SB) via 512-wide Hillis-Steele
    int c0   = (tid < SB) ? lcnt[tid] : 0;
    int idx1 = tid + 256;
    int c1   = (idx1 < SB) ? lcnt[idx1] : 0;
    ls[tid]  = c0;
    ls[idx1] = c1;
    __syncthreads();
    for (int off = 1; off < 512; off <<= 1) {
        int a0 = (tid  >= off) ? ls[tid  - off] : 0;
        int a1 = (idx1 >= off) ? ls[idx1 - off] : 0;
        __syncthreads();
        ls[tid]  += a0;
        ls[idx1] += a1;
        __syncthreads();
    }
    if (tid  < SB) pfx[tid]  = ls[tid]  - c0;
    if (idx1 < SB) pfx[idx1] = ls[idx1] - c1;
    __syncthreads();

    // rank + reorder into LDS (bucket-sorted order)
    #pragma unroll
    for (int k = 0; k < RPT; ++k) {
        if (rt[k] != 0xFFFFFFFFu) {
            int b = (int)(rt[k] >> LOGWB);
            int r = atomicAdd(&lrank[b], 1);
            int pos = pfx[b] + r;
            fv[pos] = rv[k];
            fs[pos] = (unsigned char)(rt[k] & (WB - 1));
        }
    }
    __syncthreads();

    // coalesced write-out; bucket recovered by 9-step binary search on pfx
    for (int p = tid; p < cnt_here; p += 256) {
        int loB = 0, hiB = SB;
        #pragma unroll
        for (int it = 0; it < 9; ++it) {
            int mid = (loB + hiB) >> 1;
            if (pfx[mid] <= p) loB = mid; else hiB = mid;
        }
        int dst = tb[loB] + (p - pfx[loB]);
        val[dst]     = fv[p];
        slotArr[dst] = fs[p];
    }

    // global sum of lh over events (log_nom enters the loss only as a total)
    float rl = block_reduce_sum(xl, sdata);
    if (tid == 0) atomicAdd(&acc[2], (double)rl);
}

// ---- P4: per-slice 256-slot LDS histogram, native ds_add_f32, tiny LDS ---
// grid = SB * KS blocks of 256 threads; plain-store partials, no global atomics.
__global__ void bucket_hist_kernel(const float* __restrict__ val,
                                   const unsigned char* __restrict__ slotArr,
                                   const int* __restrict__ base,
                                   float* __restrict__ partials) {
    __shared__ float hs[WB], hm[WB], ht[WB];
    int tid = threadIdx.x;
    hs[tid] = 0.f; hm[tid] = 0.f; ht[tid] = 0.f;
    __syncthreads();
    int b = blockIdx.x >> 2;              // KS == 4
    int k = blockIdx.x & (KS - 1);
    int lo0 = base[b], len = base[b + 1] - lo0;
    int lo  = lo0 + (int)(((long long)len * k) / KS);
    int hi  = lo0 + (int)(((long long)len * (k + 1)) / KS);
    for (int i = lo + tid; i < hi; i += 256) {
        float v = val[i];
        int   s = (int)slotArr[i];
        float h = fabsf(v);
        unsafeAtomicAdd(&hs[s], h);               // ds_add_f32, no return
        if (__float_as_uint(v) >> 31) {
            unsafeAtomicAdd(&hm[s], 1.0f);
            unsafeAtomicAdd(&ht[s], h);
        }
    }
    __syncthreads();
    float* pbase = partials + (size_t)blockIdx.x * 3 * WB;
    pbase[0 * WB + tid] = hs[tid];
    pbase[1 * WB + tid] = hm[tid];
    pbase[2 * WB + tid] = ht[tid];
}

// ---- P5: merge partials over slices -> per-t arrays + chunk sums ---------
__global__ void merge_kernel(const float* __restrict__ partials,
                             float* __restrict__ sum_hz,
                             float* __restrict__ mcnt,
                             float* __restrict__ ties,
                             float* __restrict__ chunk_sum) {
    __shared__ float sdata[4];
    int tid = threadIdx.x;
    int b   = blockIdx.x;
    float sh = 0.f, cm = 0.f, th = 0.f;
    #pragma unroll
    for (int k = 0; k < KS; ++k) {
        const float* pbase = partials + (size_t)(b * KS + k) * 3 * WB;
        sh += pbase[0 * WB + tid];
        cm += pbase[1 * WB + tid];
        th += pbase[2 * WB + tid];
    }
    int t = (b << LOGWB) + tid;
    float shv = (t < TMAXV) ? sh : 0.f;
    if (t < TMAXV) {
        sum_hz[t] = sh;
        mcnt[t]   = cm;
        ties[t]   = th;
    }
    float cs = block_reduce_sum(shv, sdata);
    if (tid == 0) chunk_sum[b] = cs;
}

// ---- P6: exclusive suffix scan of chunk sums (double) ----
__global__ void chunk_scan_kernel(const float* __restrict__ chunk_sum,
                                  double* __restrict__ chunk_off) {
    __shared__ double ds[512];
    int tid = threadIdx.x;
    double own = (tid < NCHUNK) ? (double)chunk_sum[tid] : 0.0;
    ds[tid] = own;
    __syncthreads();
    for (int off = 1; off < 512; off <<= 1) {
        double add = (tid + off < 512) ? ds[tid + off] : 0.0;
        __syncthreads();
        ds[tid] += add;
        __syncthreads();
    }
    if (tid < NCHUNK) chunk_off[tid] = ds[tid] - own;  // strict-suffix sum
}

// ---- P7: fused within-chunk suffix scan + Efron term + reduction ---------
__global__ void pll_suffix_kernel(const float* __restrict__ sum_hz,
                                  const float* __restrict__ mcnt,
                                  const float* __restrict__ ties,
                                  const double* __restrict__ chunk_off,
                                  double* __restrict__ acc) {
    __shared__ float sf[CHUNK];
    __shared__ float sdata[4];
    __shared__ float sdata2[4];
    int tid = threadIdx.x;
    int t   = blockIdx.x * CHUNK + tid;
    float v = (t < TMAXV) ? sum_hz[t] : 0.0f;
    sf[tid] = v;
    __syncthreads();
    for (int off = 1; off < CHUNK; off <<= 1) {
        float add = (tid + off < CHUNK) ? sf[tid + off] : 0.0f;
        __syncthreads();
        sf[tid] += add;
        __syncthreads();
    }
    float pll = 0.0f, inc = 0.0f;
    if (t < TMAXV) {
        float mv = mcnt[t];
        if (mv > 0.5f) {
            float D    = (float)(chunk_off[blockIdx.x] + (double)sf[tid]);
            float T    = ties[t];
            int   mi   = (int)(mv + 0.5f);
            float step = T / mv;
            float s = 0.0f;
            for (int l = 0; l < mi; ++l)
                s += __logf(D - (float)l * step);
            pll = -s;            // log_nom handled globally via acc[2]
            inc = 1.0f;
        }
    }
    float rp = block_reduce_sum(pll, sdata);
    __syncthreads();
    float ri = block_reduce_sum(inc, sdata2);
    if (threadIdx.x == 0) {
        atomicAdd(&acc[0], (double)rp);
        atomicAdd(&acc[1], (double)ri);
    }
}

// ---- finalize: loss = -(sum log_nom + sum(-log_denom)) / count ----
__global__ void finalize_kernel(const double* __restrict__ acc,
                                float* __restrict__ out) {
    double cnt = acc[1];
    out[0] = (cnt > 0.0) ? (float)(-(acc[0] + acc[2]) / cnt) : 0.0f;
}

// ================= FALLBACK: round-1 global-atomic histogram ==============
__global__ void hist_kernel(const float* __restrict__ lh,
                            const int*   __restrict__ tgt,
                            const int*   __restrict__ ev,
                            float* __restrict__ sum_hz,
                            float* __restrict__ mcnt,
                            float* __restrict__ log_nom,
                            float* __restrict__ ties,
                            int n) {
    int i = blockIdx.x * blockDim.x + threadIdx.x;
    if (i >= n) return;
    float x = lh[i];
    int   t = tgt[i];
    int   e = ev[i];
    float h = __expf(x);
    unsafeAtomicAdd(&sum_hz[t], h);
    if (e) {
        unsafeAtomicAdd(&mcnt[t], 1.0f);
        unsafeAtomicAdd(&log_nom[t], x);
        unsafeAtomicAdd(&ties[t], h);
    }
}

__global__ void chunk_sum_kernel(const float* __restrict__ sum_hz,
                                 float* __restrict__ chunk_sum) {
    __shared__ float sdata[4];
    int i = blockIdx.x * CHUNK + threadIdx.x;
    float v = (i < TMAXV) ? sum_hz[i] : 0.0f;
    v = block_reduce_sum(v, sdata);
    if (threadIdx.x == 0) chunk_sum[blockIdx.x] = v;
}

__global__ void pll_kernel(const float* __restrict__ mcnt,
                           const float* __restrict__ log_nom,
                           const float* __restrict__ ties,
                           const float* __restrict__ sum_hz,
                           const double* __restrict__ chunk_off,
                           double* __restrict__ acc) {
    __shared__ float sf[CHUNK];
    __shared__ float sdata[4];
    __shared__ float sdata2[4];
    int tid = threadIdx.x;
    int t   = blockIdx.x * CHUNK + tid;
    float v = (t < TMAXV) ? sum_hz[t] : 0.0f;
    sf[tid] = v;
    __syncthreads();
    for (int off = 1; off < CHUNK; off <<= 1) {
        float add = (tid + off < CHUNK) ? sf[tid + off] : 0.0f;
        __syncthreads();
        sf[tid] += add;
        __syncthreads();
    }
    float pll = 0.0f, inc = 0.0f;
    if (t < TMAXV) {
        float mv = mcnt[t];
        if (mv > 0.5f) {
            float D    = (float)(chunk_off[blockIdx.x] + (double)sf[tid]);
            float T    = ties[t];
            int   mi   = (int)(mv + 0.5f);
            float step = T / mv;
            float s = 0.0f;
            for (int l = 0; l < mi; ++l)
                s += __logf(D - (float)l * step);
            pll = log_nom[t] - s;
            inc = 1.0f;
        }
    }
    float rp = block_reduce_sum(pll, sdata);
    __syncthreads();
    float ri = block_reduce_sum(inc, sdata2);
    if (threadIdx.x == 0) {
        atomicAdd(&acc[0], (double)rp);
        atomicAdd(&acc[1], (double)ri);
    }
}

// =========================================================================
extern "C" void kernel_launch(void* const* d_in, const int* in_sizes, int n_in,
                              void* d_out, int out_size, void* d_ws, size_t ws_size,
                              hipStream_t stream) {
    const float* lh  = (const float*)d_in[0];
    const int*   tgt = (const int*)d_in[1];
    const int*   ev  = (const int*)d_in[2];
    float*       out = (float*)d_out;
    int n  = in_sizes[0];
    int nt = (n + TILE - 1) / TILE;   // number of tiles

    char* ws = (char*)d_ws;
    size_t off = 0;
    auto take = [&](size_t bytes, size_t align) {
        off = (off + align - 1) & ~(align - 1);
        size_t r = off; off += bytes; return r;
    };
    size_t o_acc    = take(32, 16);                           // 3 doubles, zeroed
    size_t o_sum    = take((size_t)TMAXV * 4, 16);
    size_t o_m      = take((size_t)TMAXV * 4, 16);
    size_t o_ties   = take((size_t)TMAXV * 4, 16);
    size_t o_base   = take((size_t)(SB + 1) * 4, 4);
    size_t o_totals = take((size_t)SB * 4, 4);
    size_t o_csum   = take((size_t)NCHUNK * 4, 16);
    size_t o_coff   = take((size_t)NCHUNK * 8, 8);
    size_t o_blkcnt = take((size_t)nt * SB * 4, 16);
    size_t o_tbase  = take((size_t)nt * SB * 4, 16);
    size_t o_val    = take((size_t)n * 4, 16);
    size_t o_slot   = take((size_t)n, 16);
    // partials overlaid on blkcnt/tilebase (dead after scatter)
    size_t part_sz  = (size_t)SB * KS * 3 * WB * 4;           // ~4.8 MB
    size_t o_part   = o_blkcnt;
    size_t need     = off;
    if (o_part + part_sz > need) need = o_part + part_sz;

    if (ws_size >= need) {
        // ================= fast path =================
        double* acc      = (double*)(ws + o_acc);
        float*  sum_hz   = (float*)(ws + o_sum);
        float*  mcnt     = (float*)(ws + o_m);
        float*  ties     = (float*)(ws + o_ties);
        int*    base     = (int*)(ws + o_base);
        int*    totals   = (int*)(ws + o_totals);
        float*  chunk_sum= (float*)(ws + o_csum);
        double* chunk_off= (double*)(ws + o_coff);
        int*    blkcnt   = (int*)(ws + o_blkcnt);
        int*    tilebase = (int*)(ws + o_tbase);
        float*  val      = (float*)(ws + o_val);
        unsigned char* slotArr = (unsigned char*)(ws + o_slot);
        float*  partials = (float*)(ws + o_part);

        hipMemsetAsync(d_ws, 0, 32, stream);   // acc only

        count_kernel<<<nt, 256, 0, stream>>>(tgt, blkcnt, n, nt);
        tile_scan_kernel<<<SB, 256, 0, stream>>>(blkcnt, tilebase, totals, nt);
        bucket_base_kernel<<<1, 512, 0, stream>>>(totals, base, n);
        scatter_kernel<<<nt, 256, 0, stream>>>(lh, tgt, ev, tilebase, base, val, slotArr, acc, n, nt);
        bucket_hist_kernel<<<SB * KS, 256, 0, stream>>>(val, slotArr, base, partials);
        merge_kernel<<<SB, 256, 0, stream>>>(partials, sum_hz, mcnt, ties, chunk_sum);
        chunk_scan_kernel<<<1, 512, 0, stream>>>(chunk_sum, chunk_off);
        pll_suffix_kernel<<<NCHUNK, 256, 0, stream>>>(sum_hz, mcnt, ties, chunk_off, acc);
        finalize_kernel<<<1, 1, 0, stream>>>(acc, out);
    } else {
        // ================= fallback (round-1 style) =================
        size_t f = 0;
        auto ftake = [&](size_t bytes, size_t align) {
            f = (f + align - 1) & ~(align - 1);
            size_t r = f; f += bytes; return r;
        };
        size_t f_acc  = ftake(32, 16);
        size_t f_sum  = ftake((size_t)TMAXV * 4, 16);
        size_t f_m    = ftake((size_t)TMAXV * 4, 16);
        size_t f_ln   = ftake((size_t)TMAXV * 4, 16);
        size_t f_ties = ftake((size_t)TMAXV * 4, 16);
        size_t zb     = f;
        size_t f_csum = ftake((size_t)NCHUNK * 4, 16);
        size_t f_coff = ftake((size_t)NCHUNK * 8, 8);

        double* acc     = (double*)(ws + f_acc);
        float*  sum_hz  = (float*)(ws + f_sum);
        float*  mcnt    = (float*)(ws + f_m);
        float*  log_nom = (float*)(ws + f_ln);
        float*  ties    = (float*)(ws + f_ties);
        float*  chunk_sum = (float*)(ws + f_csum);
        double* chunk_off = (double*)(ws + f_coff);

        hipMemsetAsync(d_ws, 0, zb, stream);

        hist_kernel<<<(n + 255) / 256, 256, 0, stream>>>(lh, tgt, ev, sum_hz, mcnt, log_nom, ties, n);
        chunk_sum_kernel<<<NCHUNK, 256, 0, stream>>>(sum_hz, chunk_sum);
        chunk_scan_kernel<<<1, 512, 0, stream>>>(chunk_sum, chunk_off);
        pll_kernel<<<NCHUNK, 256, 0, stream>>>(mcnt, log_nom, ties, sum_hz, chunk_off, acc);
        finalize_kernel<<<1, 1, 0, stream>>>(acc, out);
    }
}

// Round 7
// 246.006 us; speedup vs baseline: 1.3096x; 1.3096x over previous
//
#include <hip/hip_runtime.h>

#define TMAXV 100000
#define CHUNK 256
#define NCHUNK ((TMAXV + CHUNK - 1) / CHUNK)   // 391
#define WB 256                                  // bucket width in t
#define LOGWB 8
#define SB ((TMAXV + WB - 1) / WB)              // 391 buckets
#define TILE 4096
#define RPT 16                                  // records per thread (TILE/256)
#define KS 8                                    // slices per bucket in hist phase
#define CAP 4096                                // records per LDS pass in hist
#define RPH (CAP / 256)                         // 16

// ---------------- block reduce helper (blockDim.x == 256) ----------------
__device__ __forceinline__ float block_reduce_sum(float v, float* sdata) {
    int lane = threadIdx.x & 63;
    int wid  = threadIdx.x >> 6;
    #pragma unroll
    for (int off = 32; off > 0; off >>= 1)
        v += __shfl_down(v, off, 64);
    if (lane == 0) sdata[wid] = v;
    __syncthreads();
    if (wid == 0) {
        v = (lane < 4) ? sdata[lane] : 0.0f;
        v += __shfl_down(v, 2, 64);
        v += __shfl_down(v, 1, 64);
    }
    return v;  // valid in thread 0
}

// ================= FAST PATH: atomic-free tiled counting sort =============

// ---- P1: per-tile bucket counts (LDS), no global atomics ----
__global__ void count_kernel(const int* __restrict__ tgt,
                             int* __restrict__ blkcnt, int n, int nt) {
    __shared__ int lc[SB];
    for (int i = threadIdx.x; i < SB; i += blockDim.x) lc[i] = 0;
    __syncthreads();
    int tile = blockIdx.x;
    int lo = tile * TILE;
    int hi = min(n, lo + TILE);
    for (int i = lo + threadIdx.x; i < hi; i += blockDim.x)
        atomicAdd(&lc[tgt[i] >> LOGWB], 1);
    __syncthreads();
    for (int s = threadIdx.x; s < SB; s += blockDim.x)
        blkcnt[s * nt + tile] = lc[s];
}

// ---- P2a: per-bucket exclusive scan over tiles ----
__global__ void tile_scan_kernel(const int* __restrict__ blkcnt,
                                 int* __restrict__ tilebase,
                                 int* __restrict__ totals, int nt) {
    __shared__ int ls[256];
    int s   = blockIdx.x;
    int tid = threadIdx.x;
    int run = 0;
    for (int t0 = 0; t0 < nt; t0 += 256) {
        int t = t0 + tid;
        int c = (t < nt) ? blkcnt[s * nt + t] : 0;
        ls[tid] = c;
        __syncthreads();
        for (int off = 1; off < 256; off <<= 1) {
            int a = (tid >= off) ? ls[tid - off] : 0;
            __syncthreads();
            ls[tid] += a;
            __syncthreads();
        }
        int incl = ls[tid];
        int tot  = ls[255];
        if (t < nt) tilebase[s * nt + t] = run + incl - c;
        run += tot;
        __syncthreads();
    }
    if (tid == 0) totals[s] = run;
}

// ---- P2b: exclusive scan of bucket totals -> base (512 threads) ----
__global__ void bucket_base_kernel(const int* __restrict__ totals,
                                   int* __restrict__ base, int n) {
    __shared__ int ls[512];
    int tid = threadIdx.x;
    int c = (tid < SB) ? totals[tid] : 0;
    ls[tid] = c;
    __syncthreads();
    for (int off = 1; off < 512; off <<= 1) {
        int a = (tid >= off) ? ls[tid - off] : 0;
        __syncthreads();
        ls[tid] += a;
        __syncthreads();
    }
    if (tid < SB) base[tid] = ls[tid] - c;
    if (tid == 0) base[SB] = n;
}

// ---- P3: LDS-staged scatter of 5-byte records (val + slot byte) ----------
// val sign bit = event flag; log_nom total reduced here into acc[2].
__global__ void scatter_kernel(const float* __restrict__ lh,
                               const int*   __restrict__ tgt,
                               const int*   __restrict__ ev,
                               const int*   __restrict__ tilebase,
                               const int*   __restrict__ base,
                               float* __restrict__ val,
                               unsigned char* __restrict__ slotArr,
                               double* __restrict__ acc, int n, int nt) {
    __shared__ float fv[TILE];              // 16 KB
    __shared__ unsigned char fs[TILE];      // 4 KB
    __shared__ int lcnt[SB];
    __shared__ int pfx[SB];
    __shared__ int lrank[SB];
    __shared__ int tb[SB];
    __shared__ int ls[512];
    __shared__ float sdata[4];
    int tid  = threadIdx.x;
    int tile = blockIdx.x;
    int lo   = tile * TILE;
    int cnt_here = min(TILE, n - lo);

    for (int s = tid; s < SB; s += 256) {
        lcnt[s]  = 0;
        lrank[s] = 0;
        tb[s]    = base[s] + tilebase[s * nt + tile];
    }
    __syncthreads();

    float    rv[RPT];
    unsigned rt[RPT];
    float xl = 0.f;
    #pragma unroll
    for (int k = 0; k < RPT; ++k) {
        int i = lo + k * 256 + tid;
        if (i < n) {
            int t = tgt[i];
            int e = ev[i] & 1;
            float x = lh[i];
            float h = __expf(x);
            rv[k] = e ? -h : h;
            rt[k] = (unsigned)t;
            if (e) xl += x;
            atomicAdd(&lcnt[t >> LOGWB], 1);
        } else {
            rt[k] = 0xFFFFFFFFu;
        }
    }
    __syncthreads();

    // exclusive scan of lcnt[0..SB) via 512-wide Hillis-Steele
    int c0   = (tid < SB) ? lcnt[tid] : 0;
    int idx1 = tid + 256;
    int c1   = (idx1 < SB) ? lcnt[idx1] : 0;
    ls[tid]  = c0;
    ls[idx1] = c1;
    __syncthreads();
    for (int off = 1; off < 512; off <<= 1) {
        int a0 = (tid  >= off) ? ls[tid  - off] : 0;
        int a1 = (idx1 >= off) ? ls[idx1 - off] : 0;
        __syncthreads();
        ls[tid]  += a0;
        ls[idx1] += a1;
        __syncthreads();
    }
    if (tid  < SB) pfx[tid]  = ls[tid]  - c0;
    if (idx1 < SB) pfx[idx1] = ls[idx1] - c1;
    __syncthreads();

    // rank + reorder into LDS (bucket-sorted order)
    #pragma unroll
    for (int k = 0; k < RPT; ++k) {
        if (rt[k] != 0xFFFFFFFFu) {
            int b = (int)(rt[k] >> LOGWB);
            int r = atomicAdd(&lrank[b], 1);
            int pos = pfx[b] + r;
            fv[pos] = rv[k];
            fs[pos] = (unsigned char)(rt[k] & (WB - 1));
        }
    }
    __syncthreads();

    // coalesced write-out; bucket recovered by 9-step binary search on pfx
    for (int p = tid; p < cnt_here; p += 256) {
        int loB = 0, hiB = SB;
        #pragma unroll
        for (int it = 0; it < 9; ++it) {
            int mid = (loB + hiB) >> 1;
            if (pfx[mid] <= p) loB = mid; else hiB = mid;
        }
        int dst = tb[loB] + (p - pfx[loB]);
        val[dst]     = fv[p];
        slotArr[dst] = fs[p];
    }

    // global sum of lh over events (log_nom enters the loss only as a total)
    float rl = block_reduce_sum(xl, sdata);
    if (tid == 0) atomicAdd(&acc[2], (double)rl);
}

// ---- P4: per-slice LDS counting sort + serial per-slot reduction ---------
// grid = SB * KS blocks of 256 threads; NO fp atomics anywhere.
__global__ void bucket_hist_kernel(const float* __restrict__ val,
                                   const unsigned char* __restrict__ slotArr,
                                   const int* __restrict__ base,
                                   float* __restrict__ partials) {
    __shared__ float fv[CAP];            // 16 KB, slot-sorted values
    __shared__ unsigned cnt[WB];
    __shared__ unsigned rankc[WB];
    __shared__ unsigned pfx[WB];
    __shared__ unsigned ls[WB];
    int tid = threadIdx.x;
    int b   = blockIdx.x >> 3;           // KS == 8
    int k   = blockIdx.x & (KS - 1);
    int lo0 = base[b], len = base[b + 1] - lo0;
    int lo  = lo0 + (int)(((long long)len * k) / KS);
    int hi  = lo0 + (int)(((long long)len * (k + 1)) / KS);

    float sh = 0.f, cm = 0.f, th = 0.f;

    for (int c0 = lo; c0 < hi; c0 += CAP) {
        int c1 = min(hi, c0 + CAP);
        cnt[tid] = 0; rankc[tid] = 0;
        __syncthreads();

        float rv[RPH];
        int   rs[RPH];
        #pragma unroll
        for (int u = 0; u < RPH; ++u) {
            int i = c0 + u * 256 + tid;
            if (i < c1) {
                rv[u] = val[i];
                rs[u] = (int)slotArr[i];
                atomicAdd(&cnt[rs[u]], 1u);      // native ds_add_u32
            } else {
                rs[u] = -1;
            }
        }
        __syncthreads();

        // exclusive scan of cnt -> pfx
        unsigned c = cnt[tid];
        ls[tid] = c;
        __syncthreads();
        for (int off = 1; off < 256; off <<= 1) {
            unsigned a = (tid >= off) ? ls[tid - off] : 0u;
            __syncthreads();
            ls[tid] += a;
            __syncthreads();
        }
        pfx[tid] = ls[tid] - c;
        __syncthreads();

        // permute values into slot-sorted LDS order (slot implied by segment)
        #pragma unroll
        for (int u = 0; u < RPH; ++u) {
            if (rs[u] >= 0) {
                unsigned r = atomicAdd(&rankc[rs[u]], 1u);
                fv[pfx[rs[u]] + r] = rv[u];
            }
        }
        __syncthreads();

        // thread tid serially reduces slot tid's contiguous segment
        int s0 = (int)pfx[tid], e0 = s0 + (int)cnt[tid];
        for (int p = s0; p < e0; ++p) {
            float v = fv[p];
            float h = fabsf(v);
            sh += h;
            if (__float_as_uint(v) >> 31) { cm += 1.0f; th += h; }
        }
        __syncthreads();
    }

    // plain coalesced stores of this slice's partial histograms
    float* pbase = partials + (size_t)blockIdx.x * 3 * WB;
    pbase[0 * WB + tid] = sh;
    pbase[1 * WB + tid] = cm;
    pbase[2 * WB + tid] = th;
}

// ---- P5: merge partials over slices -> per-t arrays + chunk sums ---------
__global__ void merge_kernel(const float* __restrict__ partials,
                             float* __restrict__ sum_hz,
                             float* __restrict__ mcnt,
                             float* __restrict__ ties,
                             float* __restrict__ chunk_sum) {
    __shared__ float sdata[4];
    int tid = threadIdx.x;
    int b   = blockIdx.x;
    float sh = 0.f, cm = 0.f, th = 0.f;
    #pragma unroll
    for (int k = 0; k < KS; ++k) {
        const float* pbase = partials + (size_t)(b * KS + k) * 3 * WB;
        sh += pbase[0 * WB + tid];
        cm += pbase[1 * WB + tid];
        th += pbase[2 * WB + tid];
    }
    int t = (b << LOGWB) + tid;
    float shv = (t < TMAXV) ? sh : 0.f;
    if (t < TMAXV) {
        sum_hz[t] = sh;
        mcnt[t]   = cm;
        ties[t]   = th;
    }
    float cs = block_reduce_sum(shv, sdata);
    if (tid == 0) chunk_sum[b] = cs;
}

// ---- P6: exclusive suffix scan of chunk sums (double) ----
__global__ void chunk_scan_kernel(const float* __restrict__ chunk_sum,
                                  double* __restrict__ chunk_off) {
    __shared__ double ds[512];
    int tid = threadIdx.x;
    double own = (tid < NCHUNK) ? (double)chunk_sum[tid] : 0.0;
    ds[tid] = own;
    __syncthreads();
    for (int off = 1; off < 512; off <<= 1) {
        double add = (tid + off < 512) ? ds[tid + off] : 0.0;
        __syncthreads();
        ds[tid] += add;
        __syncthreads();
    }
    if (tid < NCHUNK) chunk_off[tid] = ds[tid] - own;  // strict-suffix sum
}

// ---- P7: fused within-chunk suffix scan + Efron term + reduction ---------
__global__ void pll_suffix_kernel(const float* __restrict__ sum_hz,
                                  const float* __restrict__ mcnt,
                                  const float* __restrict__ ties,
                                  const double* __restrict__ chunk_off,
                                  double* __restrict__ acc) {
    __shared__ float sf[CHUNK];
    __shared__ float sdata[4];
    __shared__ float sdata2[4];
    int tid = threadIdx.x;
    int t   = blockIdx.x * CHUNK + tid;
    float v = (t < TMAXV) ? sum_hz[t] : 0.0f;
    sf[tid] = v;
    __syncthreads();
    for (int off = 1; off < CHUNK; off <<= 1) {
        float add = (tid + off < CHUNK) ? sf[tid + off] : 0.0f;
        __syncthreads();
        sf[tid] += add;
        __syncthreads();
    }
    float pll = 0.0f, inc = 0.0f;
    if (t < TMAXV) {
        float mv = mcnt[t];
        if (mv > 0.5f) {
            float D    = (float)(chunk_off[blockIdx.x] + (double)sf[tid]);
            float T    = ties[t];
            int   mi   = (int)(mv + 0.5f);
            float step = T / mv;
            float s = 0.0f;
            for (int l = 0; l < mi; ++l)
                s += __logf(D - (float)l * step);
            pll = -s;            // log_nom handled globally via acc[2]
            inc = 1.0f;
        }
    }
    float rp = block_reduce_sum(pll, sdata);
    __syncthreads();
    float ri = block_reduce_sum(inc, sdata2);
    if (threadIdx.x == 0) {
        atomicAdd(&acc[0], (double)rp);
        atomicAdd(&acc[1], (double)ri);
    }
}

// ---- finalize: loss = -(sum log_nom + sum(-log_denom)) / count ----
__global__ void finalize_kernel(const double* __restrict__ acc,
                                float* __restrict__ out) {
    double cnt = acc[1];
    out[0] = (cnt > 0.0) ? (float)(-(acc[0] + acc[2]) / cnt) : 0.0f;
}

// ================= FALLBACK: round-1 global-atomic histogram ==============
__global__ void hist_kernel(const float* __restrict__ lh,
                            const int*   __restrict__ tgt,
                            const int*   __restrict__ ev,
                            float* __restrict__ sum_hz,
                            float* __restrict__ mcnt,
                            float* __restrict__ log_nom,
                            float* __restrict__ ties,
                            int n) {
    int i = blockIdx.x * blockDim.x + threadIdx.x;
    if (i >= n) return;
    float x = lh[i];
    int   t = tgt[i];
    int   e = ev[i];
    float h = __expf(x);
    unsafeAtomicAdd(&sum_hz[t], h);
    if (e) {
        unsafeAtomicAdd(&mcnt[t], 1.0f);
        unsafeAtomicAdd(&log_nom[t], x);
        unsafeAtomicAdd(&ties[t], h);
    }
}

__global__ void chunk_sum_kernel(const float* __restrict__ sum_hz,
                                 float* __restrict__ chunk_sum) {
    __shared__ float sdata[4];
    int i = blockIdx.x * CHUNK + threadIdx.x;
    float v = (i < TMAXV) ? sum_hz[i] : 0.0f;
    v = block_reduce_sum(v, sdata);
    if (threadIdx.x == 0) chunk_sum[blockIdx.x] = v;
}

__global__ void pll_kernel(const float* __restrict__ mcnt,
                           const float* __restrict__ log_nom,
                           const float* __restrict__ ties,
                           const float* __restrict__ sum_hz,
                           const double* __restrict__ chunk_off,
                           double* __restrict__ acc) {
    __shared__ float sf[CHUNK];
    __shared__ float sdata[4];
    __shared__ float sdata2[4];
    int tid = threadIdx.x;
    int t   = blockIdx.x * CHUNK + tid;
    float v = (t < TMAXV) ? sum_hz[t] : 0.0f;
    sf[tid] = v;
    __syncthreads();
    for (int off = 1; off < CHUNK; off <<= 1) {
        float add = (tid + off < CHUNK) ? sf[tid + off] : 0.0f;
        __syncthreads();
        sf[tid] += add;
        __syncthreads();
    }
    float pll = 0.0f, inc = 0.0f;
    if (t < TMAXV) {
        float mv = mcnt[t];
        if (mv > 0.5f) {
            float D    = (float)(chunk_off[blockIdx.x] + (double)sf[tid]);
            float T    = ties[t];
            int   mi   = (int)(mv + 0.5f);
            float step = T / mv;
            float s = 0.0f;
            for (int l = 0; l < mi; ++l)
                s += __logf(D - (float)l * step);
            pll = log_nom[t] - s;
            inc = 1.0f;
        }
    }
    float rp = block_reduce_sum(pll, sdata);
    __syncthreads();
    float ri = block_reduce_sum(inc, sdata2);
    if (threadIdx.x == 0) {
        atomicAdd(&acc[0], (double)rp);
        atomicAdd(&acc[1], (double)ri);
    }
}

// =========================================================================
extern "C" void kernel_launch(void* const* d_in, const int* in_sizes, int n_in,
                              void* d_out, int out_size, void* d_ws, size_t ws_size,
                              hipStream_t stream) {
    const float* lh  = (const float*)d_in[0];
    const int*   tgt = (const int*)d_in[1];
    const int*   ev  = (const int*)d_in[2];
    float*       out = (float*)d_out;
    int n  = in_sizes[0];
    int nt = (n + TILE - 1) / TILE;   // number of tiles

    char* ws = (char*)d_ws;
    size_t off = 0;
    auto take = [&](size_t bytes, size_t align) {
        off = (off + align - 1) & ~(align - 1);
        size_t r = off; off += bytes; return r;
    };
    size_t o_acc    = take(32, 16);                           // 3 doubles, zeroed
    size_t o_sum    = take((size_t)TMAXV * 4, 16);
    size_t o_m      = take((size_t)TMAXV * 4, 16);
    size_t o_ties   = take((size_t)TMAXV * 4, 16);
    size_t o_base   = take((size_t)(SB + 1) * 4, 4);
    size_t o_totals = take((size_t)SB * 4, 4);
    size_t o_csum   = take((size_t)NCHUNK * 4, 16);
    size_t o_coff   = take((size_t)NCHUNK * 8, 8);
    size_t o_blkcnt = take((size_t)nt * SB * 4, 16);
    size_t o_tbase  = take((size_t)nt * SB * 4, 16);
    size_t o_val    = take((size_t)n * 4, 16);
    size_t o_slot   = take((size_t)n, 16);
    size_t o_part   = take((size_t)SB * KS * 3 * WB * 4, 16); // ~9.6 MB
    size_t need     = off;

    if (ws_size >= need) {
        // ================= fast path =================
        double* acc      = (double*)(ws + o_acc);
        float*  sum_hz   = (float*)(ws + o_sum);
        float*  mcnt     = (float*)(ws + o_m);
        float*  ties     = (float*)(ws + o_ties);
        int*    base     = (int*)(ws + o_base);
        int*    totals   = (int*)(ws + o_totals);
        float*  chunk_sum= (float*)(ws + o_csum);
        double* chunk_off= (double*)(ws + o_coff);
        int*    blkcnt   = (int*)(ws + o_blkcnt);
        int*    tilebase = (int*)(ws + o_tbase);
        float*  val      = (float*)(ws + o_val);
        unsigned char* slotArr = (unsigned char*)(ws + o_slot);
        float*  partials = (float*)(ws + o_part);

        hipMemsetAsync(d_ws, 0, 32, stream);   // acc only

        count_kernel<<<nt, 256, 0, stream>>>(tgt, blkcnt, n, nt);
        tile_scan_kernel<<<SB, 256, 0, stream>>>(blkcnt, tilebase, totals, nt);
        bucket_base_kernel<<<1, 512, 0, stream>>>(totals, base, n);
        scatter_kernel<<<nt, 256, 0, stream>>>(lh, tgt, ev, tilebase, base, val, slotArr, acc, n, nt);
        bucket_hist_kernel<<<SB * KS, 256, 0, stream>>>(val, slotArr, base, partials);
        merge_kernel<<<SB, 256, 0, stream>>>(partials, sum_hz, mcnt, ties, chunk_sum);
        chunk_scan_kernel<<<1, 512, 0, stream>>>(chunk_sum, chunk_off);
        pll_suffix_kernel<<<NCHUNK, 256, 0, stream>>>(sum_hz, mcnt, ties, chunk_off, acc);
        finalize_kernel<<<1, 1, 0, stream>>>(acc, out);
    } else {
        // ================= fallback (round-1 style) =================
        size_t f = 0;
        auto ftake = [&](size_t bytes, size_t align) {
            f = (f + align - 1) & ~(align - 1);
            size_t r = f; f += bytes; return r;
        };
        size_t f_acc  = ftake(32, 16);
        size_t f_sum  = ftake((size_t)TMAXV * 4, 16);
        size_t f_m    = ftake((size_t)TMAXV * 4, 16);
        size_t f_ln   = ftake((size_t)TMAXV * 4, 16);
        size_t f_ties = ftake((size_t)TMAXV * 4, 16);
        size_t zb     = f;
        size_t f_csum = ftake((size_t)NCHUNK * 4, 16);
        size_t f_coff = ftake((size_t)NCHUNK * 8, 8);

        double* acc     = (double*)(ws + f_acc);
        float*  sum_hz  = (float*)(ws + f_sum);
        float*  mcnt    = (float*)(ws + f_m);
        float*  log_nom = (float*)(ws + f_ln);
        float*  ties    = (float*)(ws + f_ties);
        float*  chunk_sum = (float*)(ws + f_csum);
        double* chunk_off = (double*)(ws + f_coff);

        hipMemsetAsync(d_ws, 0, zb, stream);

        hist_kernel<<<(n + 255) / 256, 256, 0, stream>>>(lh, tgt, ev, sum_hz, mcnt, log_nom, ties, n);
        chunk_sum_kernel<<<NCHUNK, 256, 0, stream>>>(sum_hz, chunk_sum);
        chunk_scan_kernel<<<1, 512, 0, stream>>>(chunk_sum, chunk_off);
        pll_kernel<<<NCHUNK, 256, 0, stream>>>(mcnt, log_nom, ties, sum_hz, chunk_off, acc);
        finalize_kernel<<<1, 1, 0, stream>>>(acc, out);
    }
}

// Round 8
// 242.872 us; speedup vs baseline: 1.3265x; 1.0129x over previous
//
#include <hip/hip_runtime.h>

#define TMAXV 100000
#define CHUNK 256
#define NCHUNK ((TMAXV + CHUNK - 1) / CHUNK)   // 391
#define WB 256                                  // bucket width in t
#define LOGWB 8
#define SB ((TMAXV + WB - 1) / WB)              // 391 buckets
#define TILE 4096
#define RPT 16                                  // records per thread (TILE/256)
#define KS 8                                    // slices per bucket in hist phase
#define CAP 4096                                // records per LDS pass in hist
#define RPH (CAP / 256)                         // 16

// record encoding (32 bits): [31]=event  [30:8]=h=exp(x) sign/exp/high-mantissa
// [7:0]=slot (t & 255) stuffed into low mantissa bits of h (<=2^-15 rel error).
// decode: slot=bits&255, ev=bits>>31, h=fabsf(asfloat(bits)).

// ---------------- block reduce helper (blockDim.x == 256) ----------------
__device__ __forceinline__ float block_reduce_sum(float v, float* sdata) {
    int lane = threadIdx.x & 63;
    int wid  = threadIdx.x >> 6;
    #pragma unroll
    for (int off = 32; off > 0; off >>= 1)
        v += __shfl_down(v, off, 64);
    if (lane == 0) sdata[wid] = v;
    __syncthreads();
    if (wid == 0) {
        v = (lane < 4) ? sdata[lane] : 0.0f;
        v += __shfl_down(v, 2, 64);
        v += __shfl_down(v, 1, 64);
    }
    return v;  // valid in thread 0
}

// ================= FAST PATH: atomic-free tiled counting sort =============

// ---- P1: per-tile bucket counts (LDS), no global atomics ----
__global__ void count_kernel(const int* __restrict__ tgt,
                             int* __restrict__ blkcnt, int n, int nt) {
    __shared__ int lc[SB];
    for (int i = threadIdx.x; i < SB; i += blockDim.x) lc[i] = 0;
    __syncthreads();
    int tile = blockIdx.x;
    int lo = tile * TILE;
    int hi = min(n, lo + TILE);
    for (int i = lo + threadIdx.x; i < hi; i += blockDim.x)
        atomicAdd(&lc[tgt[i] >> LOGWB], 1);
    __syncthreads();
    for (int s = threadIdx.x; s < SB; s += blockDim.x)
        blkcnt[s * nt + tile] = lc[s];
}

// ---- P2a: per-bucket exclusive scan over tiles ----
__global__ void tile_scan_kernel(const int* __restrict__ blkcnt,
                                 int* __restrict__ tilebase,
                                 int* __restrict__ totals, int nt) {
    __shared__ int ls[256];
    int s   = blockIdx.x;
    int tid = threadIdx.x;
    int run = 0;
    for (int t0 = 0; t0 < nt; t0 += 256) {
        int t = t0 + tid;
        int c = (t < nt) ? blkcnt[s * nt + t] : 0;
        ls[tid] = c;
        __syncthreads();
        for (int off = 1; off < 256; off <<= 1) {
            int a = (tid >= off) ? ls[tid - off] : 0;
            __syncthreads();
            ls[tid] += a;
            __syncthreads();
        }
        int incl = ls[tid];
        int tot  = ls[255];
        if (t < nt) tilebase[s * nt + t] = run + incl - c;
        run += tot;
        __syncthreads();
    }
    if (tid == 0) totals[s] = run;
}

// ---- P2b: exclusive scan of bucket totals -> base (512 threads) ----
__global__ void bucket_base_kernel(const int* __restrict__ totals,
                                   int* __restrict__ base, int n) {
    __shared__ int ls[512];
    int tid = threadIdx.x;
    int c = (tid < SB) ? totals[tid] : 0;
    ls[tid] = c;
    __syncthreads();
    for (int off = 1; off < 512; off <<= 1) {
        int a = (tid >= off) ? ls[tid - off] : 0;
        __syncthreads();
        ls[tid] += a;
        __syncthreads();
    }
    if (tid < SB) base[tid] = ls[tid] - c;
    if (tid == 0) base[SB] = n;
}

// ---- P3: LDS-staged scatter of fused 4-byte records ----------------------
// lcnt comes from blkcnt (no re-count); log_nom total reduced into acc[2].
__global__ void scatter_kernel(const float* __restrict__ lh,
                               const int*   __restrict__ tgt,
                               const int*   __restrict__ ev,
                               const int*   __restrict__ blkcnt,
                               const int*   __restrict__ tilebase,
                               const int*   __restrict__ base,
                               unsigned* __restrict__ val,
                               double* __restrict__ acc, int n, int nt) {
    __shared__ unsigned fu[TILE];           // 16 KB
    __shared__ int pfx[SB];
    __shared__ int lrank[SB];
    __shared__ int tb[SB];
    __shared__ int ls[512];
    __shared__ float sdata[4];
    int tid  = threadIdx.x;
    int tile = blockIdx.x;
    int lo   = tile * TILE;
    int cnt_here = min(TILE, n - lo);

    // per-bucket counts for this tile already computed by count_kernel
    int c0   = (tid < SB)  ? blkcnt[tid  * nt + tile] : 0;
    int idx1 = tid + 256;
    int c1   = (idx1 < SB) ? blkcnt[idx1 * nt + tile] : 0;
    for (int s = tid; s < SB; s += 256) {
        lrank[s] = 0;
        tb[s]    = base[s] + tilebase[s * nt + tile];
    }
    ls[tid]  = c0;
    ls[idx1] = c1;
    __syncthreads();
    for (int off = 1; off < 512; off <<= 1) {
        int a0 = (tid  >= off) ? ls[tid  - off] : 0;
        int a1 = (idx1 >= off) ? ls[idx1 - off] : 0;
        __syncthreads();
        ls[tid]  += a0;
        ls[idx1] += a1;
        __syncthreads();
    }
    if (tid  < SB) pfx[tid]  = ls[tid]  - c0;
    if (idx1 < SB) pfx[idx1] = ls[idx1] - c1;

    // load + encode records into registers
    unsigned rb[RPT];
    int      rk[RPT];
    float xl = 0.f;
    #pragma unroll
    for (int k = 0; k < RPT; ++k) {
        int i = lo + k * 256 + tid;
        if (i < n) {
            int t = tgt[i];
            int e = ev[i] & 1;
            float x = lh[i];
            float h = __expf(x);
            unsigned bits = (__float_as_uint(h) & 0x7FFFFF00u)
                          | (unsigned)(t & (WB - 1))
                          | ((unsigned)e << 31);
            rb[k] = bits;
            rk[k] = t >> LOGWB;
            if (e) xl += x;
        } else {
            rk[k] = -1;
        }
    }
    __syncthreads();

    // rank + reorder into LDS (bucket-sorted order)
    #pragma unroll
    for (int k = 0; k < RPT; ++k) {
        if (rk[k] >= 0) {
            int r = atomicAdd(&lrank[rk[k]], 1);
            fu[pfx[rk[k]] + r] = rb[k];
        }
    }
    __syncthreads();

    // coalesced write-out; bucket recovered by 9-step binary search on pfx
    for (int p = tid; p < cnt_here; p += 256) {
        int loB = 0, hiB = SB;
        #pragma unroll
        for (int it = 0; it < 9; ++it) {
            int mid = (loB + hiB) >> 1;
            if (pfx[mid] <= p) loB = mid; else hiB = mid;
        }
        val[tb[loB] + (p - pfx[loB])] = fu[p];
    }

    // global sum of lh over events (log_nom enters the loss only as a total)
    float rl = block_reduce_sum(xl, sdata);
    if (tid == 0) atomicAdd(&acc[2], (double)rl);
}

// ---- P4: per-slice LDS counting sort + serial per-slot reduction ---------
// grid = SB * KS blocks of 256 threads; NO fp atomics anywhere.
__global__ void bucket_hist_kernel(const unsigned* __restrict__ val,
                                   const int* __restrict__ base,
                                   float* __restrict__ partials) {
    __shared__ unsigned fv[CAP];         // 16 KB, slot-sorted records
    __shared__ unsigned cnt[WB];
    __shared__ unsigned rankc[WB];
    __shared__ unsigned pfx[WB];
    __shared__ unsigned ls[WB];
    int tid = threadIdx.x;
    int b   = blockIdx.x >> 3;           // KS == 8
    int k   = blockIdx.x & (KS - 1);
    int lo0 = base[b], len = base[b + 1] - lo0;
    int lo  = lo0 + (int)(((long long)len * k) / KS);
    int hi  = lo0 + (int)(((long long)len * (k + 1)) / KS);

    float sh = 0.f, cm = 0.f, th = 0.f;

    for (int c0 = lo; c0 < hi; c0 += CAP) {
        int c1 = min(hi, c0 + CAP);
        cnt[tid] = 0; rankc[tid] = 0;
        __syncthreads();

        unsigned rv[RPH];
        int      rs[RPH];
        #pragma unroll
        for (int u = 0; u < RPH; ++u) {
            int i = c0 + u * 256 + tid;
            if (i < c1) {
                rv[u] = val[i];
                rs[u] = (int)(rv[u] & (WB - 1));
                atomicAdd(&cnt[rs[u]], 1u);      // native ds_add_u32
            } else {
                rs[u] = -1;
            }
        }
        __syncthreads();

        // exclusive scan of cnt -> pfx
        unsigned c = cnt[tid];
        ls[tid] = c;
        __syncthreads();
        for (int off = 1; off < 256; off <<= 1) {
            unsigned a = (tid >= off) ? ls[tid - off] : 0u;
            __syncthreads();
            ls[tid] += a;
            __syncthreads();
        }
        pfx[tid] = ls[tid] - c;
        __syncthreads();

        // permute records into slot-sorted LDS order
        #pragma unroll
        for (int u = 0; u < RPH; ++u) {
            if (rs[u] >= 0) {
                unsigned r = atomicAdd(&rankc[rs[u]], 1u);
                fv[pfx[rs[u]] + r] = rv[u];
            }
        }
        __syncthreads();

        // thread tid serially reduces slot tid's contiguous segment
        int s0 = (int)pfx[tid], e0 = s0 + (int)cnt[tid];
        for (int p = s0; p < e0; ++p) {
            unsigned bits = fv[p];
            float h = fabsf(__uint_as_float(bits));
            sh += h;
            if (bits >> 31) { cm += 1.0f; th += h; }
        }
        __syncthreads();
    }

    // plain coalesced stores of this slice's partial histograms
    float* pbase = partials + (size_t)blockIdx.x * 3 * WB;
    pbase[0 * WB + tid] = sh;
    pbase[1 * WB + tid] = cm;
    pbase[2 * WB + tid] = th;
}

// ---- P5: merge partials over slices -> per-t arrays + chunk sums ---------
__global__ void merge_kernel(const float* __restrict__ partials,
                             float* __restrict__ sum_hz,
                             float* __restrict__ mcnt,
                             float* __restrict__ ties,
                             float* __restrict__ chunk_sum) {
    __shared__ float sdata[4];
    int tid = threadIdx.x;
    int b   = blockIdx.x;
    float sh = 0.f, cm = 0.f, th = 0.f;
    #pragma unroll
    for (int k = 0; k < KS; ++k) {
        const float* pbase = partials + (size_t)(b * KS + k) * 3 * WB;
        sh += pbase[0 * WB + tid];
        cm += pbase[1 * WB + tid];
        th += pbase[2 * WB + tid];
    }
    int t = (b << LOGWB) + tid;
    float shv = (t < TMAXV) ? sh : 0.f;
    if (t < TMAXV) {
        sum_hz[t] = sh;
        mcnt[t]   = cm;
        ties[t]   = th;
    }
    float cs = block_reduce_sum(shv, sdata);
    if (tid == 0) chunk_sum[b] = cs;
}

// ---- P6: exclusive suffix scan of chunk sums (double) ----
__global__ void chunk_scan_kernel(const float* __restrict__ chunk_sum,
                                  double* __restrict__ chunk_off) {
    __shared__ double ds[512];
    int tid = threadIdx.x;
    double own = (tid < NCHUNK) ? (double)chunk_sum[tid] : 0.0;
    ds[tid] = own;
    __syncthreads();
    for (int off = 1; off < 512; off <<= 1) {
        double add = (tid + off < 512) ? ds[tid + off] : 0.0;
        __syncthreads();
        ds[tid] += add;
        __syncthreads();
    }
    if (tid < NCHUNK) chunk_off[tid] = ds[tid] - own;  // strict-suffix sum
}

// ---- P7: fused within-chunk suffix scan + Efron term + reduction ---------
__global__ void pll_suffix_kernel(const float* __restrict__ sum_hz,
                                  const float* __restrict__ mcnt,
                                  const float* __restrict__ ties,
                                  const double* __restrict__ chunk_off,
                                  double* __restrict__ acc) {
    __shared__ float sf[CHUNK];
    __shared__ float sdata[4];
    __shared__ float sdata2[4];
    int tid = threadIdx.x;
    int t   = blockIdx.x * CHUNK + tid;
    float v = (t < TMAXV) ? sum_hz[t] : 0.0f;
    sf[tid] = v;
    __syncthreads();
    for (int off = 1; off < CHUNK; off <<= 1) {
        float add = (tid + off < CHUNK) ? sf[tid + off] : 0.0f;
        __syncthreads();
        sf[tid] += add;
        __syncthreads();
    }
    float pll = 0.0f, inc = 0.0f;
    if (t < TMAXV) {
        float mv = mcnt[t];
        if (mv > 0.5f) {
            float D    = (float)(chunk_off[blockIdx.x] + (double)sf[tid]);
            float T    = ties[t];
            int   mi   = (int)(mv + 0.5f);
            float step = T / mv;
            float s = 0.0f;
            for (int l = 0; l < mi; ++l)
                s += __logf(D - (float)l * step);
            pll = -s;            // log_nom handled globally via acc[2]
            inc = 1.0f;
        }
    }
    float rp = block_reduce_sum(pll, sdata);
    __syncthreads();
    float ri = block_reduce_sum(inc, sdata2);
    if (threadIdx.x == 0) {
        atomicAdd(&acc[0], (double)rp);
        atomicAdd(&acc[1], (double)ri);
    }
}

// ---- finalize: loss = -(sum log_nom + sum(-log_denom)) / count ----
__global__ void finalize_kernel(const double* __restrict__ acc,
                                float* __restrict__ out) {
    double cnt = acc[1];
    out[0] = (cnt > 0.0) ? (float)(-(acc[0] + acc[2]) / cnt) : 0.0f;
}

// ================= FALLBACK: round-1 global-atomic histogram ==============
__global__ void hist_kernel(const float* __restrict__ lh,
                            const int*   __restrict__ tgt,
                            const int*   __restrict__ ev,
                            float* __restrict__ sum_hz,
                            float* __restrict__ mcnt,
                            float* __restrict__ log_nom,
                            float* __restrict__ ties,
                            int n) {
    int i = blockIdx.x * blockDim.x + threadIdx.x;
    if (i >= n) return;
    float x = lh[i];
    int   t = tgt[i];
    int   e = ev[i];
    float h = __expf(x);
    unsafeAtomicAdd(&sum_hz[t], h);
    if (e) {
        unsafeAtomicAdd(&mcnt[t], 1.0f);
        unsafeAtomicAdd(&log_nom[t], x);
        unsafeAtomicAdd(&ties[t], h);
    }
}

__global__ void chunk_sum_kernel(const float* __restrict__ sum_hz,
                                 float* __restrict__ chunk_sum) {
    __shared__ float sdata[4];
    int i = blockIdx.x * CHUNK + threadIdx.x;
    float v = (i < TMAXV) ? sum_hz[i] : 0.0f;
    v = block_reduce_sum(v, sdata);
    if (threadIdx.x == 0) chunk_sum[blockIdx.x] = v;
}

__global__ void pll_kernel(const float* __restrict__ mcnt,
                           const float* __restrict__ log_nom,
                           const float* __restrict__ ties,
                           const float* __restrict__ sum_hz,
                           const double* __restrict__ chunk_off,
                           double* __restrict__ acc) {
    __shared__ float sf[CHUNK];
    __shared__ float sdata[4];
    __shared__ float sdata2[4];
    int tid = threadIdx.x;
    int t   = blockIdx.x * CHUNK + tid;
    float v = (t < TMAXV) ? sum_hz[t] : 0.0f;
    sf[tid] = v;
    __syncthreads();
    for (int off = 1; off < CHUNK; off <<= 1) {
        float add = (tid + off < CHUNK) ? sf[tid + off] : 0.0f;
        __syncthreads();
        sf[tid] += add;
        __syncthreads();
    }
    float pll = 0.0f, inc = 0.0f;
    if (t < TMAXV) {
        float mv = mcnt[t];
        if (mv > 0.5f) {
            float D    = (float)(chunk_off[blockIdx.x] + (double)sf[tid]);
            float T    = ties[t];
            int   mi   = (int)(mv + 0.5f);
            float step = T / mv;
            float s = 0.0f;
            for (int l = 0; l < mi; ++l)
                s += __logf(D - (float)l * step);
            pll = log_nom[t] - s;
            inc = 1.0f;
        }
    }
    float rp = block_reduce_sum(pll, sdata);
    __syncthreads();
    float ri = block_reduce_sum(inc, sdata2);
    if (threadIdx.x == 0) {
        atomicAdd(&acc[0], (double)rp);
        atomicAdd(&acc[1], (double)ri);
    }
}

// =========================================================================
extern "C" void kernel_launch(void* const* d_in, const int* in_sizes, int n_in,
                              void* d_out, int out_size, void* d_ws, size_t ws_size,
                              hipStream_t stream) {
    const float* lh  = (const float*)d_in[0];
    const int*   tgt = (const int*)d_in[1];
    const int*   ev  = (const int*)d_in[2];
    float*       out = (float*)d_out;
    int n  = in_sizes[0];
    int nt = (n + TILE - 1) / TILE;   // number of tiles

    char* ws = (char*)d_ws;
    size_t off = 0;
    auto take = [&](size_t bytes, size_t align) {
        off = (off + align - 1) & ~(align - 1);
        size_t r = off; off += bytes; return r;
    };
    size_t o_acc    = take(32, 16);                           // 3 doubles, zeroed
    size_t o_sum    = take((size_t)TMAXV * 4, 16);
    size_t o_m      = take((size_t)TMAXV * 4, 16);
    size_t o_ties   = take((size_t)TMAXV * 4, 16);
    size_t o_base   = take((size_t)(SB + 1) * 4, 4);
    size_t o_totals = take((size_t)SB * 4, 4);
    size_t o_csum   = take((size_t)NCHUNK * 4, 16);
    size_t o_coff   = take((size_t)NCHUNK * 8, 8);
    size_t o_blkcnt = take((size_t)nt * SB * 4, 16);
    size_t o_tbase  = take((size_t)nt * SB * 4, 16);
    size_t o_val    = take((size_t)n * 4, 16);
    size_t o_part   = take((size_t)SB * KS * 3 * WB * 4, 16); // ~9.6 MB
    size_t need     = off;

    if (ws_size >= need) {
        // ================= fast path =================
        double*   acc      = (double*)(ws + o_acc);
        float*    sum_hz   = (float*)(ws + o_sum);
        float*    mcnt     = (float*)(ws + o_m);
        float*    ties     = (float*)(ws + o_ties);
        int*      base     = (int*)(ws + o_base);
        int*      totals   = (int*)(ws + o_totals);
        float*    chunk_sum= (float*)(ws + o_csum);
        double*   chunk_off= (double*)(ws + o_coff);
        int*      blkcnt   = (int*)(ws + o_blkcnt);
        int*      tilebase = (int*)(ws + o_tbase);
        unsigned* val      = (unsigned*)(ws + o_val);
        float*    partials = (float*)(ws + o_part);

        hipMemsetAsync(d_ws, 0, 32, stream);   // acc only

        count_kernel<<<nt, 256, 0, stream>>>(tgt, blkcnt, n, nt);
        tile_scan_kernel<<<SB, 256, 0, stream>>>(blkcnt, tilebase, totals, nt);
        bucket_base_kernel<<<1, 512, 0, stream>>>(totals, base, n);
        scatter_kernel<<<nt, 256, 0, stream>>>(lh, tgt, ev, blkcnt, tilebase, base, val, acc, n, nt);
        bucket_hist_kernel<<<SB * KS, 256, 0, stream>>>(val, base, partials);
        merge_kernel<<<SB, 256, 0, stream>>>(partials, sum_hz, mcnt, ties, chunk_sum);
        chunk_scan_kernel<<<1, 512, 0, stream>>>(chunk_sum, chunk_off);
        pll_suffix_kernel<<<NCHUNK, 256, 0, stream>>>(sum_hz, mcnt, ties, chunk_off, acc);
        finalize_kernel<<<1, 1, 0, stream>>>(acc, out);
    } else {
        // ================= fallback (round-1 style) =================
        size_t f = 0;
        auto ftake = [&](size_t bytes, size_t align) {
            f = (f + align - 1) & ~(align - 1);
            size_t r = f; f += bytes; return r;
        };
        size_t f_acc  = ftake(32, 16);
        size_t f_sum  = ftake((size_t)TMAXV * 4, 16);
        size_t f_m    = ftake((size_t)TMAXV * 4, 16);
        size_t f_ln   = ftake((size_t)TMAXV * 4, 16);
        size_t f_ties = ftake((size_t)TMAXV * 4, 16);
        size_t zb     = f;
        size_t f_csum = ftake((size_t)NCHUNK * 4, 16);
        size_t f_coff = ftake((size_t)NCHUNK * 8, 8);

        double* acc     = (double*)(ws + f_acc);
        float*  sum_hz  = (float*)(ws + f_sum);
        float*  mcnt    = (float*)(ws + f_m);
        float*  log_nom = (float*)(ws + f_ln);
        float*  ties    = (float*)(ws + f_ties);
        float*  chunk_sum = (float*)(ws + f_csum);
        double* chunk_off = (double*)(ws + f_coff);

        hipMemsetAsync(d_ws, 0, zb, stream);

        hist_kernel<<<(n + 255) / 256, 256, 0, stream>>>(lh, tgt, ev, sum_hz, mcnt, log_nom, ties, n);
        chunk_sum_kernel<<<NCHUNK, 256, 0, stream>>>(sum_hz, chunk_sum);
        chunk_scan_kernel<<<1, 512, 0, stream>>>(chunk_sum, chunk_off);
        pll_kernel<<<NCHUNK, 256, 0, stream>>>(mcnt, log_nom, ties, sum_hz, chunk_off, acc);
        finalize_kernel<<<1, 1, 0, stream>>>(acc, out);
    }
}